// Round 1
// baseline (11213.948 us; speedup 1.0000x reference)
//
#include <hip/hip_runtime.h>
#include <math.h>

// Problem constants
#define BB 2
#define TT 1024
#define DD 1024
#define HH 16
#define DHD 64
#define HID 4096
#define LL 8
#define VV 32000

#define KT 16

// ---------------------------------------------------------------------------
// Embedding: x[b,t,:] = emb[idx[b,t],:] + pos[t,:]
// ---------------------------------------------------------------------------
__global__ __launch_bounds__(256)
void embed_k(const int* __restrict__ idx, const float* __restrict__ emb,
             const float* __restrict__ pos, float* __restrict__ x)
{
    int row = blockIdx.x;              // b*T + t
    int t = row & (TT - 1);
    int tok = idx[row];
    const float4* e4 = (const float4*)(emb + (long long)tok * DD);
    const float4* p4 = (const float4*)(pos + (long long)t * DD);
    float4* x4 = (float4*)(x + (long long)row * DD);
    float4 a = e4[threadIdx.x];
    float4 p = p4[threadIdx.x];
    x4[threadIdx.x] = make_float4(a.x + p.x, a.y + p.y, a.z + p.z, a.w + p.w);
}

// ---------------------------------------------------------------------------
// LayerNorm: one block (256 threads) per row of D=1024
// ---------------------------------------------------------------------------
__global__ __launch_bounds__(256)
void layernorm_k(const float* __restrict__ x, const float* __restrict__ g,
                 const float* __restrict__ b, float* __restrict__ out)
{
    int row = blockIdx.x;
    int tid = threadIdx.x;
    const float4* x4 = (const float4*)(x + (long long)row * DD);
    float4 v = x4[tid];

    float s = v.x + v.y + v.z + v.w;
    #pragma unroll
    for (int o = 32; o; o >>= 1) s += __shfl_down(s, o);
    __shared__ float red[4];
    if ((tid & 63) == 0) red[tid >> 6] = s;
    __syncthreads();
    float mu = (red[0] + red[1] + red[2] + red[3]) * (1.0f / DD);

    float4 d = make_float4(v.x - mu, v.y - mu, v.z - mu, v.w - mu);
    float ss = d.x * d.x + d.y * d.y + d.z * d.z + d.w * d.w;
    #pragma unroll
    for (int o = 32; o; o >>= 1) ss += __shfl_down(ss, o);
    __syncthreads();                       // everyone done reading red (mu)
    if ((tid & 63) == 0) red[tid >> 6] = ss;
    __syncthreads();
    float var = (red[0] + red[1] + red[2] + red[3]) * (1.0f / DD);
    float rs = rsqrtf(var + 1e-5f);

    float4 gg = ((const float4*)g)[tid];
    float4 bb = ((const float4*)b)[tid];
    float4 o4;
    o4.x = d.x * rs * gg.x + bb.x;
    o4.y = d.y * rs * gg.y + bb.y;
    o4.z = d.z * rs * gg.z + bb.z;
    o4.w = d.w * rs * gg.w + bb.w;
    ((float4*)(out + (long long)row * DD))[tid] = o4;
}

// ---------------------------------------------------------------------------
// Causal softmax in place over rows of length T=1024.
// ---------------------------------------------------------------------------
__global__ __launch_bounds__(256)
void softmax_causal_k(float* __restrict__ sc)
{
    long long row = blockIdx.x;
    int t = (int)(row & (TT - 1));
    float* p = sc + row * TT;
    int tid = threadIdx.x;
    float4 v = ((const float4*)p)[tid];
    float vals[4] = {v.x, v.y, v.z, v.w};
    int s0 = tid * 4;

    float m = -INFINITY;
    #pragma unroll
    for (int j = 0; j < 4; j++) if (s0 + j <= t) m = fmaxf(m, vals[j]);
    #pragma unroll
    for (int o = 32; o; o >>= 1) m = fmaxf(m, __shfl_down(m, o));
    __shared__ float red[4];
    if ((tid & 63) == 0) red[tid >> 6] = m;
    __syncthreads();
    float M = fmaxf(fmaxf(red[0], red[1]), fmaxf(red[2], red[3]));

    float e[4];
    float ssum = 0.f;
    #pragma unroll
    for (int j = 0; j < 4; j++) {
        e[j] = (s0 + j <= t) ? __expf(vals[j] - M) : 0.f;
        ssum += e[j];
    }
    #pragma unroll
    for (int o = 32; o; o >>= 1) ssum += __shfl_down(ssum, o);
    __syncthreads();
    if ((tid & 63) == 0) red[tid >> 6] = ssum;
    __syncthreads();
    float S = red[0] + red[1] + red[2] + red[3];
    float inv = 1.0f / S;
    ((float4*)p)[tid] = make_float4(e[0] * inv, e[1] * inv, e[2] * inv, e[3] * inv);
}

// ---------------------------------------------------------------------------
// Concatenate per-layer qkv weights: wcat[d][t*1024 + h*64 + e] = w_t[h][d][e]
// grid = D blocks, 256 threads; each thread moves one float4 per tensor.
// ---------------------------------------------------------------------------
__global__ __launch_bounds__(256)
void qkvcat_k(const float* __restrict__ wq, const float* __restrict__ wk,
              const float* __restrict__ wv, float* __restrict__ wcat)
{
    int d = blockIdx.x;
    int tid = threadIdx.x;
    int hh = tid >> 4;             // 0..15
    int e = (tid & 15) * 4;        // 0..60
    long long src = (long long)hh * DD * DHD + (long long)d * DHD + e;
    float4* dst = (float4*)(wcat + (long long)d * 3072);
    dst[tid]       = *(const float4*)&wq[src];
    dst[tid + 256] = *(const float4*)&wk[src];
    dst[tid + 512] = *(const float4*)&wv[src];
}

// ---------------------------------------------------------------------------
// fp32 tiled GEMM, 128xTN tile (TN = 128 or 64), 256 threads, 8x(TN/16)/thread.
// C = alpha*(A@B[^T]) [+bias] [+res] [relu]
// Batch via blockIdx.z: off = (z>>4)*s_hi + (z&15)*s_lo per operand.
// Requires: M % 128 == 0, N % TN == 0, K % 16 == 0 (true for every call).
// Per-thread micro-tile split 4+4 at stride 64 so LDS reads are <=2-way
// bank-aliased (free on CDNA4).
// ---------------------------------------------------------------------------
template <int TN, bool TRANSB>
__global__ __launch_bounds__(256, 2)
void gemm128(const float* __restrict__ A, const float* __restrict__ B,
             const float* __restrict__ bias, const float* __restrict__ res,
             float* __restrict__ C,
             int M, int N, int K, int lda, int ldb, int ldc,
             long long sAh, long long sAl, long long sBh, long long sBl,
             long long sCh, long long sCl,
             float alpha, int relu)
{
    constexpr int TM = 128;
    constexpr int RN = TN / 16;            // 8 or 4 cols per thread
    __shared__ __align__(16) float As[KT][TM + 4];
    __shared__ __align__(16) float Bs[KT][TN + 4];

    int z = blockIdx.z;
    A += (long long)(z >> 4) * sAh + (long long)(z & 15) * sAl;
    B += (long long)(z >> 4) * sBh + (long long)(z & 15) * sBl;
    long long offC = (long long)(z >> 4) * sCh + (long long)(z & 15) * sCl;
    C += offC;
    if (res) res += offC;

    int tid = threadIdx.x;
    int tx = tid & 15;
    int ty = tid >> 4;
    int bm = blockIdx.y * TM;
    int bn = blockIdx.x * TN;

    float acc[8][RN];
    #pragma unroll
    for (int i = 0; i < 8; i++)
        #pragma unroll
        for (int j = 0; j < RN; j++) acc[i][j] = 0.f;

    // loader indices (vectorized along K for A / transposed-B)
    int k4 = (tid & 3) * 4;   // 0,4,8,12
    int ma = tid >> 2;        // 0..63

    for (int k0 = 0; k0 < K; k0 += KT) {
        // ---- A tile: As[k][m] <- A[(bm+m)*lda + k0+k], float4 along k ----
        #pragma unroll
        for (int i = 0; i < 2; i++) {
            float4 a = *(const float4*)&A[(long long)(bm + ma + 64 * i) * lda + k0 + k4];
            As[k4 + 0][ma + 64 * i] = a.x;
            As[k4 + 1][ma + 64 * i] = a.y;
            As[k4 + 2][ma + 64 * i] = a.z;
            As[k4 + 3][ma + 64 * i] = a.w;
        }
        if (TRANSB) {
            // Bs[k][n] <- B[(bn+n)*ldb + k0+k], float4 along k
            #pragma unroll
            for (int i = 0; i < TN / 64; i++) {
                float4 b = *(const float4*)&B[(long long)(bn + ma + 64 * i) * ldb + k0 + k4];
                Bs[k4 + 0][ma + 64 * i] = b.x;
                Bs[k4 + 1][ma + 64 * i] = b.y;
                Bs[k4 + 2][ma + 64 * i] = b.z;
                Bs[k4 + 3][ma + 64 * i] = b.w;
            }
        } else {
            // Bs[k][n] <- B[(k0+k)*ldb + bn+n], float4 along n
            int n4 = (tid & (TN / 4 - 1)) * 4;
            int kb = tid / (TN / 4);
            #pragma unroll
            for (int i = 0; i < (KT * TN) / 1024; i++) {
                float4 b = *(const float4*)&B[(long long)(k0 + kb + (1024 / TN) * i) * ldb + bn + n4];
                *(float4*)&Bs[kb + (1024 / TN) * i][n4] = b;
            }
        }
        __syncthreads();

        #pragma unroll
        for (int k = 0; k < KT; k++) {
            float4 a0 = *(const float4*)&As[k][ty * 4];
            float4 a1 = *(const float4*)&As[k][ty * 4 + 64];
            float4 bq0 = *(const float4*)&Bs[k][tx * 4];
            float av[8] = {a0.x, a0.y, a0.z, a0.w, a1.x, a1.y, a1.z, a1.w};
            float bv[RN];
            bv[0] = bq0.x; bv[1] = bq0.y; bv[2] = bq0.z; bv[3] = bq0.w;
            if constexpr (RN == 8) {
                float4 bq1 = *(const float4*)&Bs[k][tx * 4 + 64];
                bv[4] = bq1.x; bv[5] = bq1.y; bv[6] = bq1.z; bv[7] = bq1.w;
            }
            #pragma unroll
            for (int i = 0; i < 8; i++)
                #pragma unroll
                for (int j = 0; j < RN; j++)
                    acc[i][j] += av[i] * bv[j];
        }
        __syncthreads();
    }

    // ---- epilogue ----
    float4 bs0 = make_float4(0.f, 0.f, 0.f, 0.f);
    float4 bs1 = make_float4(0.f, 0.f, 0.f, 0.f);
    if (bias) {
        bs0 = *(const float4*)&bias[bn + tx * 4];
        if constexpr (RN == 8) bs1 = *(const float4*)&bias[bn + tx * 4 + 64];
    }
    #pragma unroll
    for (int i = 0; i < 8; i++) {
        long long m = bm + ty * 4 + (i & 3) + (i >> 2) * 64;
        float* crow = C + m * ldc + bn + tx * 4;
        float4 v0;
        v0.x = acc[i][0] * alpha + bs0.x;
        v0.y = acc[i][1] * alpha + bs0.y;
        v0.z = acc[i][2] * alpha + bs0.z;
        v0.w = acc[i][3] * alpha + bs0.w;
        if (res) {
            float4 r = *(const float4*)(res + m * ldc + bn + tx * 4);
            v0.x += r.x; v0.y += r.y; v0.z += r.z; v0.w += r.w;
        }
        if (relu) {
            v0.x = fmaxf(v0.x, 0.f); v0.y = fmaxf(v0.y, 0.f);
            v0.z = fmaxf(v0.z, 0.f); v0.w = fmaxf(v0.w, 0.f);
        }
        *(float4*)crow = v0;
        if constexpr (RN == 8) {
            float4 v1;
            v1.x = acc[i][4] * alpha + bs1.x;
            v1.y = acc[i][5] * alpha + bs1.y;
            v1.z = acc[i][6] * alpha + bs1.z;
            v1.w = acc[i][7] * alpha + bs1.w;
            if (res) {
                float4 r = *(const float4*)(res + m * ldc + bn + tx * 4 + 64);
                v1.x += r.x; v1.y += r.y; v1.z += r.z; v1.w += r.w;
            }
            if (relu) {
                v1.x = fmaxf(v1.x, 0.f); v1.y = fmaxf(v1.y, 0.f);
                v1.z = fmaxf(v1.z, 0.f); v1.w = fmaxf(v1.w, 0.f);
            }
            *(float4*)(crow + 64) = v1;
        }
    }
}

// ---------------------------------------------------------------------------
// Launcher
// ---------------------------------------------------------------------------
extern "C" void kernel_launch(void* const* d_in, const int* in_sizes, int n_in,
                              void* d_out, int out_size, void* d_ws, size_t ws_size,
                              hipStream_t stream)
{
    const int*   idx   = (const int*)  d_in[0];
    const float* emb   = (const float*)d_in[1];
    const float* pos   = (const float*)d_in[2];
    const float* wq    = (const float*)d_in[3];   // [L,H,D,DH]
    const float* wk    = (const float*)d_in[4];
    const float* wv    = (const float*)d_in[5];
    const float* wo    = (const float*)d_in[6];   // [L,D,D]
    const float* w1    = (const float*)d_in[7];   // [L,D,HID]
    const float* b1    = (const float*)d_in[8];   // [L,HID]
    const float* w2    = (const float*)d_in[9];   // [L,HID,D]
    const float* b2    = (const float*)d_in[10];  // [L,D]
    const float* ln1_g = (const float*)d_in[11];
    const float* ln1_b = (const float*)d_in[12];
    const float* ln2_g = (const float*)d_in[13];
    const float* ln2_b = (const float*)d_in[14];
    const float* lnf_g = (const float*)d_in[15];
    const float* lnf_b = (const float*)d_in[16];
    float* out = (float*)d_out;

    const long long NTOK = (long long)BB * TT;        // 2048
    const long long SZ_X = NTOK * DD;                 // 2M floats

    float* x     = (float*)d_ws;
    float* h     = x    + SZ_X;
    float* qkv   = h    + SZ_X;          // [B,T, 3*H*DH] = [2048, 3072] = 6M
    float* attn  = qkv  + NTOK * 3072;   // [B,T,D] = 2M
    float* ffhid = attn + SZ_X;          // [B,T,HID] = 8M floats
    float* wcat  = ffhid;                // [D, 3072] = 3M, aliased w/ ffhid (disjoint lifetime)
    float* sc    = out;                  // scores [B,H,T,T] = 33.5M floats, d_out as scratch

    const long long sTD  = (long long)TT * DD;        // per-b stride in x/h/attn
    const long long sTQ  = (long long)TT * 3072;      // per-b stride in qkv
    const long long sTT  = (long long)TT * TT;        // per-(b,h) stride in scores
    const long long sHTT = (long long)HH * sTT;

    // x = emb[idx] + pos
    embed_k<<<dim3((unsigned)NTOK), 256, 0, stream>>>(idx, emb, pos, x);

    for (int l = 0; l < LL; l++) {
        const float* wq_l = wq + (long long)l * HH * DD * DHD;
        const float* wk_l = wk + (long long)l * HH * DD * DHD;
        const float* wv_l = wv + (long long)l * HH * DD * DHD;
        const float* wo_l = wo + (long long)l * DD * DD;
        const float* w1_l = w1 + (long long)l * DD * HID;
        const float* w2_l = w2 + (long long)l * HID * DD;

        // h = LN1(x)
        layernorm_k<<<dim3((unsigned)NTOK), 256, 0, stream>>>(
            x, ln1_g + l * DD, ln1_b + l * DD, h);

        // wcat[d][t*1024 + h*64 + e] = w{q,k,v}[l][h][d][e]
        qkvcat_k<<<dim3(DD), 256, 0, stream>>>(wq_l, wk_l, wv_l, wcat);

        // qkv = h @ wcat   (M=2048, N=3072, K=1024), single dense GEMM
        gemm128<128, false><<<dim3(3072 / 128, (unsigned)(NTOK / 128), 1), 256, 0, stream>>>(
            h, wcat, nullptr, nullptr, qkv,
            (int)NTOK, 3072, DD, DD, 3072, 3072,
            0, 0, 0, 0, 0, 0, 1.0f, 0);

        // scores[b,h] = (q[b,h] @ k[b,h]^T) * 1/sqrt(DH); q at col 0, k at col 1024
        gemm128<128, true><<<dim3(TT / 128, TT / 128, BB * HH), 256, 0, stream>>>(
            qkv, qkv + 1024, nullptr, nullptr, sc,
            TT, TT, DHD, 3072, 3072, TT,
            sTQ, DHD, sTQ, DHD, sHTT, sTT, 0.125f, 0);

        // causal softmax in place
        softmax_causal_k<<<dim3((unsigned)(BB * HH * TT)), 256, 0, stream>>>(sc);

        // attn[b, :, h*64:(h+1)*64] = scores[b,h] @ v[b,h]; v at col 2048
        gemm128<64, false><<<dim3(1, TT / 128, BB * HH), 256, 0, stream>>>(
            sc, qkv + 2048, nullptr, nullptr, attn,
            TT, DHD, TT, TT, 3072, DD,
            sHTT, sTT, sTQ, DHD, sTD, DHD, 1.0f, 0);

        // x = x + attn @ wo^T
        gemm128<64, true><<<dim3(DD / 64, (unsigned)(NTOK / 128), 1), 256, 0, stream>>>(
            attn, wo_l, nullptr, x, x,
            (int)NTOK, DD, DD, DD, DD, DD,
            0, 0, 0, 0, 0, 0, 1.0f, 0);

        // h = LN2(x)
        layernorm_k<<<dim3((unsigned)NTOK), 256, 0, stream>>>(
            x, ln2_g + l * DD, ln2_b + l * DD, h);

        // ffhid = relu(h @ w1 + b1)   (overwrites wcat alias — wcat dead here)
        gemm128<128, false><<<dim3(HID / 128, (unsigned)(NTOK / 128), 1), 256, 0, stream>>>(
            h, w1_l, b1 + (long long)l * HID, nullptr, ffhid,
            (int)NTOK, HID, DD, DD, HID, HID,
            0, 0, 0, 0, 0, 0, 1.0f, 1);

        // x = x + ffhid @ w2 + b2
        gemm128<64, false><<<dim3(DD / 64, (unsigned)(NTOK / 128), 1), 256, 0, stream>>>(
            ffhid, w2_l, b2 + (long long)l * DD, x, x,
            (int)NTOK, DD, HID, HID, DD, DD,
            0, 0, 0, 0, 0, 0, 1.0f, 0);
    }

    // h = LNf(x)
    layernorm_k<<<dim3((unsigned)NTOK), 256, 0, stream>>>(x, lnf_g, lnf_b, h);

    // logits = h @ emb^T  (M=2048, N=32000, K=1024)
    gemm128<128, true><<<dim3(VV / 128, (unsigned)(NTOK / 128), 1), 256, 0, stream>>>(
        h, emb, nullptr, nullptr, out,
        (int)NTOK, VV, DD, DD, DD, VV,
        0, 0, 0, 0, 0, 0, 1.0f, 0);
}

// Round 2
// 5207.170 us; speedup vs baseline: 2.1536x; 2.1536x over previous
//
#include <hip/hip_runtime.h>
#include <math.h>

// Problem constants
#define BB 2
#define TT 1024
#define DD 1024
#define HH 16
#define DHD 64
#define HID 4096
#define LL 8
#define VV 32000

typedef __attribute__((ext_vector_type(8))) __bf16 bf16x8;
typedef __attribute__((ext_vector_type(4))) float f32x4;

__device__ __forceinline__ unsigned short f2b(float f) {
    unsigned u = __builtin_bit_cast(unsigned, f);
    return (unsigned short)((u + 0x7FFFu + ((u >> 16) & 1u)) >> 16);   // RNE
}
__device__ __forceinline__ float b2f(unsigned short h) {
    unsigned u = (unsigned)h << 16;
    return __builtin_bit_cast(float, u);
}

// ---------------------------------------------------------------------------
// Embedding: x[b,t,:] = emb[idx[b,t],:] + pos[t,:]
// ---------------------------------------------------------------------------
__global__ __launch_bounds__(256)
void embed_k(const int* __restrict__ idx, const float* __restrict__ emb,
             const float* __restrict__ pos, float* __restrict__ x)
{
    int row = blockIdx.x;              // b*T + t
    int t = row & (TT - 1);
    int tok = idx[row];
    const float4* e4 = (const float4*)(emb + (long long)tok * DD);
    const float4* p4 = (const float4*)(pos + (long long)t * DD);
    float4* x4 = (float4*)(x + (long long)row * DD);
    float4 a = e4[threadIdx.x];
    float4 p = p4[threadIdx.x];
    x4[threadIdx.x] = make_float4(a.x + p.x, a.y + p.y, a.z + p.z, a.w + p.w);
}

// ---------------------------------------------------------------------------
// LayerNorm: one block (256 threads) per row of D=1024
// ---------------------------------------------------------------------------
__global__ __launch_bounds__(256)
void layernorm_k(const float* __restrict__ x, const float* __restrict__ g,
                 const float* __restrict__ b, float* __restrict__ out)
{
    int row = blockIdx.x;
    int tid = threadIdx.x;
    const float4* x4 = (const float4*)(x + (long long)row * DD);
    float4 v = x4[tid];

    float s = v.x + v.y + v.z + v.w;
    #pragma unroll
    for (int o = 32; o; o >>= 1) s += __shfl_down(s, o);
    __shared__ float red[4];
    if ((tid & 63) == 0) red[tid >> 6] = s;
    __syncthreads();
    float mu = (red[0] + red[1] + red[2] + red[3]) * (1.0f / DD);

    float4 d = make_float4(v.x - mu, v.y - mu, v.z - mu, v.w - mu);
    float ss = d.x * d.x + d.y * d.y + d.z * d.z + d.w * d.w;
    #pragma unroll
    for (int o = 32; o; o >>= 1) ss += __shfl_down(ss, o);
    __syncthreads();
    if ((tid & 63) == 0) red[tid >> 6] = ss;
    __syncthreads();
    float var = (red[0] + red[1] + red[2] + red[3]) * (1.0f / DD);
    float rs = rsqrtf(var + 1e-5f);

    float4 gg = ((const float4*)g)[tid];
    float4 bb = ((const float4*)b)[tid];
    float4 o4;
    o4.x = d.x * rs * gg.x + bb.x;
    o4.y = d.y * rs * gg.y + bb.y;
    o4.z = d.z * rs * gg.z + bb.z;
    o4.w = d.w * rs * gg.w + bb.w;
    ((float4*)(out + (long long)row * DD))[tid] = o4;
}

// ---------------------------------------------------------------------------
// Causal softmax in place over rows of length T=1024.
// Writes exact 0 for all j > t (so downstream K-clamping is exact).
// ---------------------------------------------------------------------------
__global__ __launch_bounds__(256)
void softmax_causal_k(float* __restrict__ sc)
{
    long long row = blockIdx.x;
    int t = (int)(row & (TT - 1));
    float* p = sc + row * TT;
    int tid = threadIdx.x;
    float4 v = ((const float4*)p)[tid];
    float vals[4] = {v.x, v.y, v.z, v.w};
    int s0 = tid * 4;

    float m = -INFINITY;
    #pragma unroll
    for (int j = 0; j < 4; j++) if (s0 + j <= t) m = fmaxf(m, vals[j]);
    #pragma unroll
    for (int o = 32; o; o >>= 1) m = fmaxf(m, __shfl_down(m, o));
    __shared__ float red[4];
    if ((tid & 63) == 0) red[tid >> 6] = m;
    __syncthreads();
    float M = fmaxf(fmaxf(red[0], red[1]), fmaxf(red[2], red[3]));

    float e[4];
    float ssum = 0.f;
    #pragma unroll
    for (int j = 0; j < 4; j++) {
        e[j] = (s0 + j <= t) ? __expf(vals[j] - M) : 0.f;
        ssum += e[j];
    }
    #pragma unroll
    for (int o = 32; o; o >>= 1) ssum += __shfl_down(ssum, o);
    __syncthreads();
    if ((tid & 63) == 0) red[tid >> 6] = ssum;
    __syncthreads();
    float S = red[0] + red[1] + red[2] + red[3];
    float inv = 1.0f / S;
    ((float4*)p)[tid] = make_float4(e[0] * inv, e[1] * inv, e[2] * inv, e[3] * inv);
}

// ---------------------------------------------------------------------------
// Tiled transpose + bf16 hi/lo split: dst[c][r] = src[r][c] as (hi, lo) planes.
// Grid: (C/64, R/64, batch). Batch off = (z>>4)*sh + (z&15)*sl per side.
// ---------------------------------------------------------------------------
__global__ __launch_bounds__(256)
void transposeSplit_k(const float* __restrict__ src,
                      unsigned short* __restrict__ dh,
                      unsigned short* __restrict__ dl,
                      int lds_, int ldd_,
                      long long sSh, long long sSl, long long sDh, long long sDl)
{
    __shared__ float T[64][65];
    int z = blockIdx.z;
    src += (long long)(z >> 4) * sSh + (long long)(z & 15) * sSl;
    long long dOff = (long long)(z >> 4) * sDh + (long long)(z & 15) * sDl;
    dh += dOff; dl += dOff;
    int r0 = blockIdx.y * 64, c0 = blockIdx.x * 64;
    int tid = threadIdx.x;
    int rr = tid >> 4, c4 = (tid & 15) * 4;
    #pragma unroll
    for (int i = 0; i < 4; i++) {
        float4 v = *(const float4*)&src[(long long)(r0 + rr + 16 * i) * lds_ + c0 + c4];
        T[rr + 16 * i][c4 + 0] = v.x;
        T[rr + 16 * i][c4 + 1] = v.y;
        T[rr + 16 * i][c4 + 2] = v.z;
        T[rr + 16 * i][c4 + 3] = v.w;
    }
    __syncthreads();
    int cc = tid >> 4, r4 = (tid & 15) * 4;
    #pragma unroll
    for (int i = 0; i < 4; i++) {
        int c = cc + 16 * i;
        float x0 = T[r4 + 0][c], x1 = T[r4 + 1][c], x2 = T[r4 + 2][c], x3 = T[r4 + 3][c];
        unsigned short h0 = f2b(x0), h1 = f2b(x1), h2 = f2b(x2), h3 = f2b(x3);
        long long o = (long long)(c0 + c) * ldd_ + r0 + r4;
        *(ushort4*)&dh[o] = make_ushort4(h0, h1, h2, h3);
        *(ushort4*)&dl[o] = make_ushort4(f2b(x0 - b2f(h0)), f2b(x1 - b2f(h1)),
                                         f2b(x2 - b2f(h2)), f2b(x3 - b2f(h3)));
    }
}

// ---------------------------------------------------------------------------
// MFMA GEMM via bf16 hi/lo split (3 products: hh + hl + lh).
// A: fp32 [M][K] (lda). B: [N][K] either fp32 (convert in staging) or
// pre-split bf16 hi/lo planes (BSPLIT). C = alpha*A@B^T [+bias][+res][relu].
// Tile BM x BN, BK=32, 256 threads = 4 waves. Wave tile: (BM/WM_WAVES) x 64.
// causal: 1 = skip tile if fully above diagonal (scores), 2 = clamp K to
// bm+BM (attn@V; P is exactly 0 beyond the diagonal).
// Batch via blockIdx.z: off = (z>>4)*s_hi + (z&15)*s_lo per operand
// (element units of the respective array).
// ---------------------------------------------------------------------------
template <int BM, int BN, bool BSPLIT>
__global__ __launch_bounds__(256)
void mgemm(const float* __restrict__ A, const void* __restrict__ Bp,
           const void* __restrict__ Bp2,
           const float* __restrict__ bias, const float* __restrict__ res,
           float* __restrict__ C, int K, int lda, int ldb, int ldc,
           long long sAh_, long long sAl_, long long sBh_, long long sBl_,
           long long sCh_, long long sCl_, float alpha, int relu, int causal)
{
    constexpr int BK = 32, BKP = 40;          // +8 bf16 pad: 2-way banks max
    constexpr int WN_WAVES = BN / 64;
    constexpr int WM_WAVES = 4 / WN_WAVES;
    constexpr int WM = BM / WM_WAVES;
    constexpr int FM = WM / 16;
    constexpr int FN = 4;

    __shared__ __align__(16) unsigned short Ah[BM][BKP];
    __shared__ __align__(16) unsigned short Al[BM][BKP];
    __shared__ __align__(16) unsigned short Bh[BN][BKP];
    __shared__ __align__(16) unsigned short Bl[BN][BKP];

    int bm = blockIdx.y * BM;
    int bn = blockIdx.x * BN;
    if (causal == 1 && bn >= bm + BM) return;          // fully-masked tile
    int Ke = (causal == 2 && bm + BM < K) ? (bm + BM) : K;

    int z = blockIdx.z;
    A += (long long)(z >> 4) * sAh_ + (long long)(z & 15) * sAl_;
    long long offB = (long long)(z >> 4) * sBh_ + (long long)(z & 15) * sBl_;
    long long offC = (long long)(z >> 4) * sCh_ + (long long)(z & 15) * sCl_;
    C += offC;
    if (res) res += offC;

    int tid = threadIdx.x;
    int lane = tid & 63;
    int wave = tid >> 6;
    int wm = wave / WN_WAVES;
    int wn = wave % WN_WAVES;
    int l15 = lane & 15;
    int kk = (lane >> 4) * 8;          // k-chunk of this lane group

    int sm = tid >> 3;                 // 0..31  (staging row)
    int sk = (tid & 7) * 4;            // 0..28  (staging k, float4)

    f32x4 acc[FM][FN];
    #pragma unroll
    for (int i = 0; i < FM; i++)
        #pragma unroll
        for (int j = 0; j < FN; j++) {
            f32x4 zr = {0.f, 0.f, 0.f, 0.f};
            acc[i][j] = zr;
        }

    for (int k0 = 0; k0 < Ke; k0 += BK) {
        // ---- stage A (fp32 -> hi/lo bf16) ----
        #pragma unroll
        for (int i = 0; i < BM / 32; i++) {
            int m = sm + 32 * i;
            float4 v = *(const float4*)&A[(long long)(bm + m) * lda + k0 + sk];
            unsigned short h0 = f2b(v.x), h1 = f2b(v.y), h2 = f2b(v.z), h3 = f2b(v.w);
            *(ushort4*)&Ah[m][sk] = make_ushort4(h0, h1, h2, h3);
            *(ushort4*)&Al[m][sk] = make_ushort4(f2b(v.x - b2f(h0)), f2b(v.y - b2f(h1)),
                                                 f2b(v.z - b2f(h2)), f2b(v.w - b2f(h3)));
        }
        // ---- stage B ----
        #pragma unroll
        for (int i = 0; i < BN / 32; i++) {
            int n = sm + 32 * i;
            if constexpr (BSPLIT) {
                const unsigned short* Bhg = (const unsigned short*)Bp + offB;
                const unsigned short* Blg = (const unsigned short*)Bp2 + offB;
                *(ushort4*)&Bh[n][sk] = *(const ushort4*)&Bhg[(long long)(bn + n) * ldb + k0 + sk];
                *(ushort4*)&Bl[n][sk] = *(const ushort4*)&Blg[(long long)(bn + n) * ldb + k0 + sk];
            } else {
                const float* Bf = (const float*)Bp + offB;
                float4 v = *(const float4*)&Bf[(long long)(bn + n) * ldb + k0 + sk];
                unsigned short h0 = f2b(v.x), h1 = f2b(v.y), h2 = f2b(v.z), h3 = f2b(v.w);
                *(ushort4*)&Bh[n][sk] = make_ushort4(h0, h1, h2, h3);
                *(ushort4*)&Bl[n][sk] = make_ushort4(f2b(v.x - b2f(h0)), f2b(v.y - b2f(h1)),
                                                     f2b(v.z - b2f(h2)), f2b(v.w - b2f(h3)));
            }
        }
        __syncthreads();

        // ---- fragments ----
        bf16x8 fah[FM], fal[FM], fbh[FN], fbl[FN];
        #pragma unroll
        for (int i = 0; i < FM; i++) {
            int r = wm * WM + i * 16 + l15;
            fah[i] = *(const bf16x8*)&Ah[r][kk];
            fal[i] = *(const bf16x8*)&Al[r][kk];
        }
        #pragma unroll
        for (int j = 0; j < FN; j++) {
            int c = wn * 64 + j * 16 + l15;
            fbh[j] = *(const bf16x8*)&Bh[c][kk];
            fbl[j] = *(const bf16x8*)&Bl[c][kk];
        }
        // ---- 3-product MFMA ----
        #pragma unroll
        for (int i = 0; i < FM; i++)
            #pragma unroll
            for (int j = 0; j < FN; j++) {
                acc[i][j] = __builtin_amdgcn_mfma_f32_16x16x32_bf16(fah[i], fbh[j], acc[i][j], 0, 0, 0);
                acc[i][j] = __builtin_amdgcn_mfma_f32_16x16x32_bf16(fah[i], fbl[j], acc[i][j], 0, 0, 0);
                acc[i][j] = __builtin_amdgcn_mfma_f32_16x16x32_bf16(fal[i], fbh[j], acc[i][j], 0, 0, 0);
            }
        __syncthreads();
    }

    // ---- epilogue: C row = (lane>>4)*4 + reg, col = lane&15 (m89 layout) ----
    int r16 = (lane >> 4) * 4;
    #pragma unroll
    for (int i = 0; i < FM; i++) {
        int rbase = bm + wm * WM + i * 16 + r16;
        #pragma unroll
        for (int j = 0; j < FN; j++) {
            int c = bn + wn * 64 + j * 16 + l15;
            float bb = bias ? bias[c] : 0.0f;
            #pragma unroll
            for (int q = 0; q < 4; q++) {
                long long off = (long long)(rbase + q) * ldc + c;
                float vv = acc[i][j][q] * alpha + bb;
                if (res) vv += res[off];
                if (relu) vv = fmaxf(vv, 0.0f);
                C[off] = vv;
            }
        }
    }
}

// ---------------------------------------------------------------------------
// Launcher
// ---------------------------------------------------------------------------
extern "C" void kernel_launch(void* const* d_in, const int* in_sizes, int n_in,
                              void* d_out, int out_size, void* d_ws, size_t ws_size,
                              hipStream_t stream)
{
    const int*   idx   = (const int*)  d_in[0];
    const float* emb   = (const float*)d_in[1];
    const float* pos   = (const float*)d_in[2];
    const float* wq    = (const float*)d_in[3];   // [L,H,D,DH]
    const float* wk    = (const float*)d_in[4];
    const float* wv    = (const float*)d_in[5];
    const float* wo    = (const float*)d_in[6];   // [L,D,D]  (= [N][K] for x@wo^T)
    const float* w1    = (const float*)d_in[7];   // [L,D,HID]
    const float* b1    = (const float*)d_in[8];
    const float* w2    = (const float*)d_in[9];   // [L,HID,D]
    const float* b2    = (const float*)d_in[10];
    const float* ln1_g = (const float*)d_in[11];
    const float* ln1_b = (const float*)d_in[12];
    const float* ln2_g = (const float*)d_in[13];
    const float* ln2_b = (const float*)d_in[14];
    const float* lnf_g = (const float*)d_in[15];
    const float* lnf_b = (const float*)d_in[16];
    float* out = (float*)d_out;

    const long long NTOK = (long long)BB * TT;        // 2048
    const long long SZ_X = NTOK * DD;                 // 2M floats

    float* x     = (float*)d_ws;
    float* h     = x    + SZ_X;
    float* qkv   = h    + SZ_X;          // [B,T,3072] = 6M floats
    float* attn  = qkv  + NTOK * 3072;   // [B,T,D]
    float* ffhid = attn + SZ_X;          // [B,T,HID] = 8M floats
    float* sc    = out;                  // scores [B,H,T,T] = 33.55M floats (d_out scratch)
    // bf16 hi/lo plane scratch in the unused tail of d_out (out = 65.5M floats):
    unsigned short* tbh = (unsigned short*)(out + 34ll * 1024 * 1024);  // 4M shorts
    unsigned short* tbl = tbh + 4ll * 1024 * 1024;                      // 4M shorts

    const long long sTD  = (long long)TT * DD;        // per-b stride in x/h/attn
    const long long sTQ  = (long long)TT * 3072;      // per-b stride in qkv
    const long long sTT  = (long long)TT * TT;        // per-(b,h) stride in scores
    const long long sHTT = (long long)HH * sTT;

    // x = emb[idx] + pos
    embed_k<<<dim3((unsigned)NTOK), 256, 0, stream>>>(idx, emb, pos, x);

    for (int l = 0; l < LL; l++) {
        const float* wq_l = wq + (long long)l * HH * DD * DHD;
        const float* wk_l = wk + (long long)l * HH * DD * DHD;
        const float* wv_l = wv + (long long)l * HH * DD * DHD;
        const float* wo_l = wo + (long long)l * DD * DD;
        const float* w1_l = w1 + (long long)l * DD * HID;
        const float* w2_l = w2 + (long long)l * HID * DD;

        // h = LN1(x)
        layernorm_k<<<dim3((unsigned)NTOK), 256, 0, stream>>>(
            x, ln1_g + l * DD, ln1_b + l * DD, h);

        // wcatT planes: [n=3072][k=1024]; per head: dst[e][d] = w[h][d][e]
        transposeSplit_k<<<dim3(1, 16, 16), 256, 0, stream>>>(
            wq_l, tbh, tbl, 64, 1024, 0, 65536, 0, 65536);
        transposeSplit_k<<<dim3(1, 16, 16), 256, 0, stream>>>(
            wk_l, tbh + 1024ll * 1024, tbl + 1024ll * 1024, 64, 1024, 0, 65536, 0, 65536);
        transposeSplit_k<<<dim3(1, 16, 16), 256, 0, stream>>>(
            wv_l, tbh + 2048ll * 1024, tbl + 2048ll * 1024, 64, 1024, 0, 65536, 0, 65536);

        // qkv = h @ wcat   (M=2048, N=3072, K=1024)
        mgemm<128, 128, true><<<dim3(24, 16, 1), 256, 0, stream>>>(
            h, tbh, tbl, nullptr, nullptr, qkv,
            DD, DD, DD, 3072, 0, 0, 0, 0, 0, 0, 1.0f, 0, 0);

        // vT planes: per (b,h): [e=64][t=1024] from qkv v-part
        transposeSplit_k<<<dim3(1, 16, 32), 256, 0, stream>>>(
            qkv + 2048, tbh, tbl, 3072, 1024, sTQ, 64, 16ll * 65536, 65536);

        // scores = 0.125 * q @ k^T per (b,h); skip fully-masked tiles
        mgemm<128, 128, false><<<dim3(8, 8, BB * HH), 256, 0, stream>>>(
            qkv, qkv + 1024, nullptr, nullptr, nullptr, sc,
            DHD, 3072, 3072, TT, sTQ, DHD, sTQ, DHD, sHTT, sTT, 0.125f, 0, 1);

        // causal softmax in place (writes exact 0 above diagonal)
        softmax_causal_k<<<dim3((unsigned)(BB * HH * TT)), 256, 0, stream>>>(sc);

        // attn[b,:,h*64:+64] = P @ v   (B = vT planes, K clamped to bm+128)
        mgemm<128, 64, true><<<dim3(1, 8, BB * HH), 256, 0, stream>>>(
            sc, tbh, tbl, nullptr, nullptr, attn,
            TT, TT, TT, DD, sHTT, sTT, 16ll * 65536, 65536, sTD, DHD, 1.0f, 0, 2);

        // x = x + attn @ wo^T   (wo already [N][K] fp32)
        mgemm<128, 64, false><<<dim3(16, 16, 1), 256, 0, stream>>>(
            attn, wo_l, nullptr, nullptr, x, x,
            DD, DD, DD, DD, 0, 0, 0, 0, 0, 0, 1.0f, 0, 0);

        // h = LN2(x)
        layernorm_k<<<dim3((unsigned)NTOK), 256, 0, stream>>>(
            x, ln2_g + l * DD, ln2_b + l * DD, h);

        // w1T planes: [4096][1024]
        transposeSplit_k<<<dim3(64, 16, 1), 256, 0, stream>>>(
            w1_l, tbh, tbl, HID, DD, 0, 0, 0, 0);

        // ffhid = relu(h @ w1 + b1)
        mgemm<128, 128, true><<<dim3(32, 16, 1), 256, 0, stream>>>(
            h, tbh, tbl, b1 + (long long)l * HID, nullptr, ffhid,
            DD, DD, DD, HID, 0, 0, 0, 0, 0, 0, 1.0f, 1, 0);

        // w2T planes: [1024][4096]
        transposeSplit_k<<<dim3(16, 64, 1), 256, 0, stream>>>(
            w2_l, tbh, tbl, DD, HID, 0, 0, 0, 0);

        // x = x + ffhid @ w2 + b2
        mgemm<128, 64, true><<<dim3(16, 16, 1), 256, 0, stream>>>(
            ffhid, tbh, tbl, b2 + (long long)l * DD, x, x,
            HID, HID, HID, DD, 0, 0, 0, 0, 0, 0, 1.0f, 0, 0);
    }

    // h = LNf(x)
    layernorm_k<<<dim3((unsigned)NTOK), 256, 0, stream>>>(x, lnf_g, lnf_b, h);

    // logits = h @ emb^T  (M=2048, N=32000, K=1024; emb is [N][K] fp32)
    mgemm<128, 128, false><<<dim3(VV / 128, 16, 1), 256, 0, stream>>>(
        h, emb, nullptr, nullptr, nullptr, out,
        DD, DD, DD, VV, 0, 0, 0, 0, 0, 0, 1.0f, 0, 0);
}